// Round 14
// baseline (51.890 us; speedup 1.0000x reference)
//
#include <hip/hip_runtime.h>
#include <math.h>

#define N_ 2
#define L_ 2048
#define H_ 8
#define E_ 64
#define D_ 64
#define C_ 128                 // chunk size
#define NC (L_/C_)             // 16
#define ROWSTRIDE (H_*E_)      // 512 floats between consecutive l
#define TEMP 0.125f            // 1/sqrt(64)
#define EPS_F 1e-6f
#define NEG_INF_F (-1e9f)
#define CHUNK_WS (E_*D_ + E_)  // 4160 floats per (n,h,chunk) ws entry
#define NCHUNKS (N_*H_*NC)     // 256
#define TPAD 136               // transposed bf16 tile row stride (shorts)
#define PPAD 72                // pbuf row stride (shorts)
#define PSTG 136               // P-staging row stride in k_pre (shorts)

typedef __attribute__((ext_vector_type(8))) short short8;   // 8 bf16 in 4 VGPRs
typedef __attribute__((ext_vector_type(4))) float f32x4;

__device__ __forceinline__ short f2bf(float x) {
  unsigned u = __float_as_uint(x);
  u += 0x7fffu + ((u >> 16) & 1u);   // round-to-nearest-even
  return (short)(u >> 16);
}
__device__ __forceinline__ float bf2f(short s) {
  return __uint_as_float(((unsigned)(unsigned short)s) << 16);
}
// tanh(x)+1 = 2/(1+exp(-2x))
__device__ __forceinline__ float tanh1f(float x) {
  float e = __expf(-2.f * x);
  return 2.f * __builtin_amdgcn_rcpf(1.f + e);
}

// Stage [128][64] f32 global tile -> swizzled bf16 LDS tile ([row][64]), f(x,row).
template <typename F>
__device__ __forceinline__ void stage_tile(short* __restrict__ dst,
                                           const float* __restrict__ src, F f) {
  const int t = threadIdx.x;
#pragma unroll
  for (int it = 0; it < 4; ++it) {
    int gi = it * 256 + t;
    int row = gi >> 3, g = gi & 7;
    const float* p = src + row * ROWSTRIDE + g * 8;
    float4 a = *(const float4*)p;
    float4 b = *(const float4*)(p + 4);
    float xs[8] = {a.x, a.y, a.z, a.w, b.x, b.y, b.z, b.w};
    short8 v;
#pragma unroll
    for (int j = 0; j < 8; ++j) v[j] = f2bf(f(xs[j], row));
    *(short8*)(dst + row * 64 + (g ^ (row & 7)) * 8) = v;
  }
}

// A/B fragment from swizzled row-major bf16 tile.
__device__ __forceinline__ short8 frag_ld(const short* __restrict__ buf,
                                          int rowbase, int hf, int lane) {
  int r = rowbase + (lane & 15);
  int g = (hf * 4 + (lane >> 4)) ^ (r & 7);
  return *(const short8*)(buf + r * 64 + g * 8);
}
// fragment from transposed padded tile [rows][TPAD].
__device__ __forceinline__ short8 frag_ldT(const short* __restrict__ buf,
                                           int nbase, int g, int lane) {
  int r = nbase + (lane & 15);
  return *(const short8*)(buf + r * TPAD + g * 8);
}
// A fragment from pbuf [64][PPAD].
__device__ __forceinline__ short8 frag_ldP(const short* __restrict__ buf,
                                           int rowbase, int ks, int lane) {
  int r = rowbase + (lane & 15);
  int g = ks * 4 + (lane >> 4);
  return *(const short8*)(buf + r * PPAD + g * 8);
}

// ---------------- Kernel 1: k_pre = denom partials + chunk sums (R13, unchanged) -----
extern "C" __global__ void __launch_bounds__(256)
k_pre(const float* __restrict__ Q, const float* __restrict__ K,
      const float* __restrict__ V, const float* __restrict__ mask,
      float* __restrict__ ws, float* __restrict__ part,
      short* __restrict__ pd, short* __restrict__ pp) {
  __shared__ short lds[17408];
  __shared__ float fmsk[C_];
  short* ldsA = lds;
  short* ldsB = lds + 8704;
  const int orig = blockIdx.x;                       // 2432 = 8 * 304
  const int swz = (orig & 7) * 304 + (orig >> 3);
  const int t = threadIdx.x;
  const int w = t >> 6, lane = t & 63;
  const int col_lo = lane & 15;

  if (swz < 2176) {
    // ---------------- denom role ----------------
    const int nh = swz / 136;
    const int p = swz - nh * 136;
    int qb = (int)((sqrtf(8.f * p + 1.f) - 1.f) * 0.5f);
    while ((qb + 1) * (qb + 2) / 2 <= p) ++qb;
    while (qb * (qb + 1) / 2 > p) --qb;
    const int kb = p - qb * (qb + 1) / 2;
    const int h = nh & (H_ - 1), n = nh >> 3;

    stage_tile(ldsA, Q + ((n * L_ + qb * C_) * H_ + h) * E_,
               [](float x, int) { return x; });
    stage_tile(ldsB, K + ((n * L_ + kb * C_) * H_ + h) * E_,
               [](float x, int) { return x; });
    if (t < C_) fmsk[t] = mask[n * L_ + kb * C_ + t];
    __syncthreads();

    const int rowbase = w * 32;
    short8 afr[2][2];
#pragma unroll
    for (int m = 0; m < 2; ++m)
#pragma unroll
      for (int hh = 0; hh < 2; ++hh)
        afr[m][hh] = frag_ld(ldsA, rowbase + 16 * m, hh, lane);

    f32x4 acc[2][8];
#pragma unroll
    for (int m = 0; m < 2; ++m)
#pragma unroll
      for (int c = 0; c < 8; ++c) acc[m][c] = (f32x4){0.f, 0.f, 0.f, 0.f};

#pragma unroll
    for (int c = 0; c < 8; ++c) {
      short8 b0 = frag_ld(ldsB, 16 * c, 0, lane);
      short8 b1 = frag_ld(ldsB, 16 * c, 1, lane);
#pragma unroll
      for (int m = 0; m < 2; ++m) {
        acc[m][c] = __builtin_amdgcn_mfma_f32_16x16x32_bf16(afr[m][0], b0, acc[m][c], 0, 0, 0);
        acc[m][c] = __builtin_amdgcn_mfma_f32_16x16x32_bf16(afr[m][1], b1, acc[m][c], 0, 0, 0);
      }
    }

    const bool diag = (kb == qb);
    const bool prev = (kb == qb - 1);
    const bool band = diag || prev;
    if (band) __syncthreads();   // tiles consumed; lds becomes P staging

    float* pout = part + (size_t)(nh * NC + qb) * C_ * 16;
#pragma unroll
    for (int m = 0; m < 2; ++m) {
      const int rbase = rowbase + 16 * m + ((lane >> 4) << 2);
      float rs[4] = {0.f, 0.f, 0.f, 0.f};
#pragma unroll
      for (int c = 0; c < 8; ++c) {
        const int col = 16 * c + col_lo;
        const float madd = (fmsk[col] > 0.f) ? 0.f : NEG_INF_F;
#pragma unroll
        for (int reg = 0; reg < 4; ++reg) {
          float x = acc[m][c][reg] + madd;
          if (diag && col > rbase + reg) x += NEG_INF_F;
          float e = __expf(x * TEMP);
          rs[reg] += e;                              // denominator: full causal range
          if (band) {
            if (prev && col < rbase + reg) e = 0.f;  // band: keep s >= l - 128
            lds[(rbase + reg) * PSTG + col] = f2bf(e);
          }
        }
      }
#pragma unroll
      for (int off = 1; off < 16; off <<= 1) {
#pragma unroll
        for (int reg = 0; reg < 4; ++reg) rs[reg] += __shfl_xor(rs[reg], off);
      }
      if (col_lo == 0) {
#pragma unroll
        for (int reg = 0; reg < 4; ++reg) pout[(rbase + reg) * 16 + kb] = rs[reg];
      }
    }

    if (band) {
      __syncthreads();   // all P values staged
      short* pt = (diag ? pd : pp) + (size_t)(nh * NC + qb) * (C_ * C_);
#pragma unroll
      for (int i = 0; i < 8; ++i) {
        int flat = i * 256 + t;          // short8 granule 0..2047
        int row = flat >> 4, g = flat & 15;
        *(short8*)(pt + row * C_ + g * 8) =
            *(const short8*)(lds + row * PSTG + g * 8);   // coalesced
      }
    }
  } else {
    // ---------------- chunk-sums role (bf16 MFMA) ----------------
    const int id = swz - 2176;               // 0..255
    const int nh = id >> 4, c = id & 15;
    const int h = nh & (H_ - 1), n = nh >> 3;
    const int gbase = ((n * L_ + c * C_) * H_ + h) * E_;
    const int e = t & 63, sb = t >> 6;
    const int mbase = n * L_ + c * C_;
#pragma unroll
    for (int q = 0; q < 4; ++q) {
      int s0 = sb * 32 + q * 8;
      short8 kk, vv;
#pragma unroll
      for (int j = 0; j < 8; ++j) {
        float kx = K[gbase + (s0 + j) * ROWSTRIDE + e];
        kk[j] = f2bf(tanh1f(kx) * mask[mbase + s0 + j]);
        vv[j] = f2bf(V[gbase + (s0 + j) * ROWSTRIDE + e]);
      }
      *(short8*)(ldsA + e * TPAD + (s0 >> 3) * 8) = kk;
      *(short8*)(ldsB + e * TPAD + (s0 >> 3) * 8) = vv;
    }
    __syncthreads();

    f32x4 acc[4];
#pragma unroll
    for (int nn = 0; nn < 4; ++nn) acc[nn] = (f32x4){0.f, 0.f, 0.f, 0.f};
#pragma unroll
    for (int ks = 0; ks < 4; ++ks) {
      short8 a = frag_ldT(ldsB, 16 * w, ks * 4 + (lane >> 4), lane);
#pragma unroll
      for (int nn = 0; nn < 4; ++nn) {
        short8 b = frag_ldT(ldsA, 16 * nn, ks * 4 + (lane >> 4), lane);
        acc[nn] = __builtin_amdgcn_mfma_f32_16x16x32_bf16(a, b, acc[nn], 0, 0, 0);
      }
    }
    float* wsc = ws + (size_t)(nh * NC + c) * CHUNK_WS;
    const int drow = 16 * w + ((lane >> 4) << 2);
#pragma unroll
    for (int nn = 0; nn < 4; ++nn)
#pragma unroll
      for (int reg = 0; reg < 4; ++reg)
        wsc[(16 * nn + col_lo) * D_ + drow + reg] = acc[nn][reg];
    if (t < 64) {
      float s = 0.f;
#pragma unroll
      for (int g = 0; g < 16; ++g) {
        short8 v = *(const short8*)(ldsA + t * TPAD + g * 8);
#pragma unroll
        for (int j = 0; j < 8; ++j) s += bf2f(v[j]);
      }
      wsc[E_ * D_ + t] = s;
    }
  }
}

// ---------------- Kernel 2: exclusive prefix scan, element-parallel ------------------
extern "C" __global__ void __launch_bounds__(256)
k_scan(float* __restrict__ ws) {
  const int bid = blockIdx.x;                        // 272 = 8 * 34
  const int swz = (bid & 7) * 34 + (bid >> 3);
  const int nh = swz / 17, seg = swz - nh * 17;
  const int idx = seg * 256 + threadIdx.x;
  if (idx >= CHUNK_WS) return;
  float* base = ws + (size_t)nh * NC * CHUNK_WS + idx;
  float v[NC];
#pragma unroll
  for (int c = 0; c < NC; ++c) v[c] = base[(size_t)c * CHUNK_WS];
  float acc = 0.f;
#pragma unroll
  for (int c = 0; c < NC; ++c) {
    base[(size_t)c * CHUNK_WS] = acc;
    acc += v[c];
  }
}

// ---------------- Kernel 3: fused, D-split (grid 1024 = 4 blocks/CU) -----------------
// Block = (nh, qb, rh 64-row half, dh 32-col half). QK-linear duplicated per dh
// (MFMA-cheap); V/S^T staging and all PV phases halve; LDS 35KB -> 4 blocks/CU.
extern "C" __global__ void __launch_bounds__(256)
k_fused(const float* __restrict__ Q, const float* __restrict__ K,
        const float* __restrict__ V, const float* __restrict__ mask,
        const float* __restrict__ blend, const float* __restrict__ ws,
        const float* __restrict__ part, const short* __restrict__ pd,
        const short* __restrict__ pp, float* __restrict__ out) {
  __shared__ short kbuf[C_ * 64];    // K1 (swizzled)                    16 KB
  __shared__ short kv[32 * TPAD];    // S^T half -> V^T_cur -> V^T_prev  8.7 KB
  __shared__ short pbuf[64 * PPAD];  // wave-private P half-tiles        9.2 KB
  __shared__ float zlds[64];
  __shared__ float dinv[64];
  __shared__ float ksum[E_];

  const int orig = blockIdx.x;                      // 1024 = 8 * 128
  const int swz = (orig & 7) * 128 + (orig >> 3);
  const int dh = swz & 1, rh = (swz >> 1) & 1;
  const int qb = (swz >> 2) & (NC - 1), nh = swz >> 6;
  const int h = nh & (H_ - 1), n = nh >> 3;
  const int t = threadIdx.x;
  const int w = t >> 6, lane = t & 63;
  const int rowbase = w * 16;
  const int col_lo = lane & 15;
  const int rb = rowbase + ((lane >> 4) << 2);
  const int rtile0 = rh * 64 + rb;
  const int dd0 = dh * 32;                          // this block's d-column base
  const int qgbase = ((n * L_ + qb * C_ + rh * 64) * H_ + h) * E_;
  const int kbase_chunk = ((n * L_ + qb * C_) * H_ + h) * E_;
  const float* wsc = ws + (size_t)(nh * NC + qb) * CHUNK_WS;
  const float bl = blend[0];
  const float ob = 1.f - bl;
  const bool haveprev = (qb > 0);
  const int kgp = ((n * L_ + (qb - 1) * C_) * H_ + h) * E_;
  const int dloc = t & 31;                          // local d row (kv)

  // ===== seg0: stage K1 (full), S^T half, dinv/ksum =====
  {
    const float* mrow = mask + n * L_ + qb * C_;
#pragma unroll
    for (int it = 0; it < 4; ++it) {
      int gi = it * 256 + t, row = gi >> 3, g = gi & 7;
      const float* p = K + kbase_chunk + row * ROWSTRIDE + g * 8;
      float4 a = *(const float4*)p, b = *(const float4*)(p + 4);
      float km = mrow[row];
      float xs[8] = {a.x, a.y, a.z, a.w, b.x, b.y, b.z, b.w};
      short8 v1;
#pragma unroll
      for (int j = 0; j < 8; ++j) v1[j] = f2bf(tanh1f(xs[j]) * km);
      *(short8*)(kbuf + row * 64 + (g ^ (row & 7)) * 8) = v1;
    }
  }
  {  // S^T half into kv: row = local d, cols = e
    int eb = t >> 5;                                // 8 e-groups
    short8 v;
#pragma unroll
    for (int j = 0; j < 8; ++j) v[j] = f2bf(wsc[(eb * 8 + j) * D_ + dd0 + dloc]);
    *(short8*)(kv + dloc * TPAD + eb * 8) = v;
  }
  if (t < 64) {
    ksum[t] = wsc[E_ * D_ + t];
    const float* pb = part + ((size_t)(nh * NC + qb) * C_ + rh * 64 + t) * 16;
    float4 a = *(const float4*)pb, b = *(const float4*)(pb + 4);
    float4 c = *(const float4*)(pb + 8), d4 = *(const float4*)(pb + 12);
    float vv[16] = {a.x, a.y, a.z, a.w, b.x, b.y, b.z, b.w,
                    c.x, c.y, c.z, c.w, d4.x, d4.y, d4.z, d4.w};
    float s = 0.f;
#pragma unroll
    for (int j = 0; j < 16; ++j) s += (j <= qb) ? vv[j] : 0.f;
    dinv[t] = 1.f / s;
  }
  __syncthreads();   // B1

  // ===== seg1: af1 (Q from global), c1 = Q1K1^T (full), rowsum, zpart, accO = Q1@S^T =====
  short8 af1[2];
  {
    const float* qp = Q + qgbase + (rowbase + (lane & 15)) * ROWSTRIDE;
#pragma unroll
    for (int kh = 0; kh < 2; ++kh) {
      int c0 = (kh * 4 + (lane >> 4)) * 8;
      float4 a = *(const float4*)(qp + c0);
      float4 b = *(const float4*)(qp + c0 + 4);
      float xs[8] = {a.x, a.y, a.z, a.w, b.x, b.y, b.z, b.w};
#pragma unroll
      for (int j = 0; j < 8; ++j) af1[kh][j] = f2bf(tanh1f(xs[j]));
    }
  }
  f32x4 c1[8];
#pragma unroll
  for (int ct = 0; ct < 8; ++ct) c1[ct] = (f32x4){0.f, 0.f, 0.f, 0.f};
#pragma unroll
  for (int ct = 0; ct < 8; ++ct) {
    short8 b0 = frag_ld(kbuf, 16 * ct, 0, lane);
    short8 b1 = frag_ld(kbuf, 16 * ct, 1, lane);
    c1[ct] = __builtin_amdgcn_mfma_f32_16x16x32_bf16(af1[0], b0, c1[ct], 0, 0, 0);
    c1[ct] = __builtin_amdgcn_mfma_f32_16x16x32_bf16(af1[1], b1, c1[ct], 0, 0, 0);
  }
  {  // zpart = Q1 . Ksum_start
    float zz = 0.f;
#pragma unroll
    for (int kh = 0; kh < 2; ++kh) {
      int cb = (kh * 4 + (lane >> 4)) * 8;
#pragma unroll
      for (int j = 0; j < 8; ++j) zz += bf2f(af1[kh][j]) * ksum[cb + j];
    }
    zz += __shfl_xor(zz, 16);
    zz += __shfl_xor(zz, 32);
    if (lane < 16) zlds[rowbase + lane] = zz;
  }
  float rs[4] = {0.f, 0.f, 0.f, 0.f};
#pragma unroll
  for (int ct = 0; ct < 8; ++ct) {
    int col = 16 * ct + col_lo;
#pragma unroll
    for (int reg = 0; reg < 4; ++reg) {
      if (col <= rtile0 + reg) rs[reg] += c1[ct][reg];
      else c1[ct][reg] = 0.f;
    }
  }
#pragma unroll
  for (int off = 1; off < 16; off <<= 1)
#pragma unroll
    for (int reg = 0; reg < 4; ++reg) rs[reg] += __shfl_xor(rs[reg], off);

  f32x4 accO[2];
#pragma unroll
  for (int nn = 0; nn < 2; ++nn) accO[nn] = (f32x4){0.f, 0.f, 0.f, 0.f};
#pragma unroll
  for (int ks = 0; ks < 2; ++ks) {
    short8 bf[2];
#pragma unroll
    for (int nn = 0; nn < 2; ++nn)
      bf[nn] = frag_ldT(kv, 16 * nn, ks * 4 + (lane >> 4), lane);
#pragma unroll
    for (int nn = 0; nn < 2; ++nn)
      accO[nn] = __builtin_amdgcn_mfma_f32_16x16x32_bf16(af1[ks], bf[nn], accO[nn], 0, 0, 0);
  }
  float zrf[4], sdv[4];
#pragma unroll
  for (int reg = 0; reg < 4; ++reg) {
    zrf[reg] = ob / (zlds[rb + reg] + rs[reg] + EPS_F);
    sdv[reg] = bl * dinv[rb + reg];
  }
#pragma unroll
  for (int nn = 0; nn < 2; ++nn)
#pragma unroll
    for (int reg = 0; reg < 4; ++reg) accO[nn][reg] *= zrf[reg];
#pragma unroll
  for (int ct = 0; ct < 8; ++ct)
#pragma unroll
    for (int reg = 0; reg < 4; ++reg) c1[ct][reg] *= zrf[reg];
  __syncthreads();   // B2: kbuf + kv(S^T) free

  // ===== seg2: stage V^T_cur half into kv =====
  {
    int sb8 = t >> 5;                               // 8 s-groups of 16
#pragma unroll
    for (int q = 0; q < 2; ++q) {
      int s0 = sb8 * 16 + q * 8;
      short8 v;
#pragma unroll
      for (int j = 0; j < 8; ++j)
        v[j] = f2bf(V[kbase_chunk + (s0 + j) * ROWSTRIDE + dd0 + dloc]);
      *(short8*)(kv + dloc * TPAD + (s0 >> 3) * 8) = v;
    }
  }
  __syncthreads();   // B3

  // ===== seg3: accO += P1_hat @ V_cur (pbuf wave-local) =====
#pragma unroll
  for (int hh = 0; hh < 2; ++hh) {
#pragma unroll
    for (int cc = 0; cc < 4; ++cc) {
      int ct = 4 * hh + cc, colh = 16 * cc + col_lo;
#pragma unroll
      for (int reg = 0; reg < 4; ++reg)
        pbuf[(rb + reg) * PPAD + colh] = f2bf(c1[ct][reg]);
    }
#pragma unroll
    for (int ks = 0; ks < 2; ++ks) {
      short8 ap = frag_ldP(pbuf, rowbase, ks, lane);
      short8 bv[2];
#pragma unroll
      for (int nn = 0; nn < 2; ++nn)
        bv[nn] = frag_ldT(kv, 16 * nn, 8 * hh + ks * 4 + (lane >> 4), lane);
#pragma unroll
      for (int nn = 0; nn < 2; ++nn)
        accO[nn] = __builtin_amdgcn_mfma_f32_16x16x32_bf16(ap, bv[nn], accO[nn], 0, 0, 0);
    }
  }

  // ===== seg3b: diag P tile (precomputed) -> pbuf -> PV into accS =====
  f32x4 accS[2];
#pragma unroll
  for (int nn = 0; nn < 2; ++nn) accS[nn] = (f32x4){0.f, 0.f, 0.f, 0.f};
  {
    const short* ps = pd + (size_t)(nh * NC + qb) * (C_ * C_) + (size_t)(rh * 64) * C_;
#pragma unroll
    for (int hh = 0; hh < 2; ++hh) {
#pragma unroll
      for (int i = 0; i < 2; ++i) {   // wave-private copy of 16 rows x 64 cols half
        int idx = i * 64 + lane;
        int rl = rowbase + (idx >> 3), g = idx & 7;
        short8 v = *(const short8*)(ps + (size_t)rl * C_ + 64 * hh + g * 8);
        *(short8*)(pbuf + rl * PPAD + g * 8) = v;
      }
#pragma unroll
      for (int ks = 0; ks < 2; ++ks) {
        short8 ap = frag_ldP(pbuf, rowbase, ks, lane);
        short8 bv[2];
#pragma unroll
        for (int nn = 0; nn < 2; ++nn)
          bv[nn] = frag_ldT(kv, 16 * nn, 8 * hh + ks * 4 + (lane >> 4), lane);
#pragma unroll
        for (int nn = 0; nn < 2; ++nn)
          accS[nn] = __builtin_amdgcn_mfma_f32_16x16x32_bf16(ap, bv[nn], accS[nn], 0, 0, 0);
      }
    }
  }

  // ===== seg4/5: prev band tile =====
  if (haveprev) {
    __syncthreads();   // B4
    {
      int sb8 = t >> 5;
#pragma unroll
      for (int q = 0; q < 2; ++q) {
        int s0 = sb8 * 16 + q * 8;
        short8 v;
#pragma unroll
        for (int j = 0; j < 8; ++j)
          v[j] = f2bf(V[kgp + (s0 + j) * ROWSTRIDE + dd0 + dloc]);
        *(short8*)(kv + dloc * TPAD + (s0 >> 3) * 8) = v;
      }
    }
    __syncthreads();   // B5

    const short* ps = pp + (size_t)(nh * NC + qb) * (C_ * C_) + (size_t)(rh * 64) * C_;
#pragma unroll
    for (int hh = 0; hh < 2; ++hh) {
#pragma unroll
      for (int i = 0; i < 2; ++i) {
        int idx = i * 64 + lane;
        int rl = rowbase + (idx >> 3), g = idx & 7;
        short8 v = *(const short8*)(ps + (size_t)rl * C_ + 64 * hh + g * 8);
        *(short8*)(pbuf + rl * PPAD + g * 8) = v;
      }
#pragma unroll
      for (int ks = 0; ks < 2; ++ks) {
        short8 ap = frag_ldP(pbuf, rowbase, ks, lane);
        short8 bv[2];
#pragma unroll
        for (int nn = 0; nn < 2; ++nn)
          bv[nn] = frag_ldT(kv, 16 * nn, 8 * hh + ks * 4 + (lane >> 4), lane);
#pragma unroll
        for (int nn = 0; nn < 2; ++nn)
          accS[nn] = __builtin_amdgcn_mfma_f32_16x16x32_bf16(ap, bv[nn], accS[nn], 0, 0, 0);
      }
    }
  }

  // ===== final store: out = (folded linear) + sdv * SV_raw =====
#pragma unroll
  for (int nn = 0; nn < 2; ++nn)
#pragma unroll
    for (int reg = 0; reg < 4; ++reg)
      out[qgbase + (rb + reg) * ROWSTRIDE + dd0 + 16 * nn + col_lo] =
          accO[nn][reg] + sdv[reg] * accS[nn][reg];
}

extern "C" void kernel_launch(void* const* d_in, const int* in_sizes, int n_in,
                              void* d_out, int out_size, void* d_ws, size_t ws_size,
                              hipStream_t stream) {
  (void)in_sizes; (void)n_in; (void)out_size; (void)ws_size;
  const float* Q = (const float*)d_in[0];
  const float* K = (const float*)d_in[1];
  const float* V = (const float*)d_in[2];
  const float* mask = (const float*)d_in[3];
  const float* blend = (const float*)d_in[4];
  float* out = (float*)d_out;
  float* ws = (float*)d_ws;
  // layout (floats): chunk state | part | P_diag (bf16) | P_prev (bf16)  ~22.3 MB
  float* part = ws + (size_t)NCHUNKS * CHUNK_WS;
  short* pd = (short*)(part + (size_t)NCHUNKS * C_ * 16);
  short* pp = pd + (size_t)NCHUNKS * C_ * C_;

  k_pre<<<dim3(2432), dim3(256), 0, stream>>>(Q, K, V, mask, ws, part, pd, pp);
  k_scan<<<dim3(272), dim3(256), 0, stream>>>(ws);
  k_fused<<<dim3(1024), dim3(256), 0, stream>>>(Q, K, V, mask, blend, ws, part, pd, pp, out);
}

// Round 15
// 45.947 us; speedup vs baseline: 1.1293x; 1.1293x over previous
//
#include <hip/hip_runtime.h>
#include <math.h>

#define N_ 2
#define L_ 2048
#define H_ 8
#define E_ 64
#define D_ 64
#define C_ 128                 // chunk size
#define NC (L_/C_)             // 16
#define ROWSTRIDE (H_*E_)      // 512 floats between consecutive l
#define TEMP 0.125f            // 1/sqrt(64)
#define EPS_F 1e-6f
#define NEG_INF_F (-1e9f)
#define CHUNK_WS (E_*D_ + E_)  // 4160 floats per (n,h,chunk) ws entry
#define NCHUNKS (N_*H_*NC)     // 256
#define TPAD 136               // transposed bf16 tile row stride (shorts)
#define PPAD 72                // pbuf row stride (shorts)

typedef __attribute__((ext_vector_type(8))) short short8;   // 8 bf16 in 4 VGPRs
typedef __attribute__((ext_vector_type(4))) float f32x4;

__device__ __forceinline__ short f2bf(float x) {
  unsigned u = __float_as_uint(x);
  u += 0x7fffu + ((u >> 16) & 1u);   // round-to-nearest-even
  return (short)(u >> 16);
}
__device__ __forceinline__ float bf2f(short s) {
  return __uint_as_float(((unsigned)(unsigned short)s) << 16);
}
// tanh(x)+1 = 2/(1+exp(-2x))
__device__ __forceinline__ float tanh1f(float x) {
  float e = __expf(-2.f * x);
  return 2.f * __builtin_amdgcn_rcpf(1.f + e);
}

// Stage [128][64] f32 global tile -> swizzled bf16 LDS tile ([row][64]), f(x,row).
template <typename F>
__device__ __forceinline__ void stage_tile(short* __restrict__ dst,
                                           const float* __restrict__ src, F f) {
  const int t = threadIdx.x;
#pragma unroll
  for (int it = 0; it < 4; ++it) {
    int gi = it * 256 + t;
    int row = gi >> 3, g = gi & 7;
    const float* p = src + row * ROWSTRIDE + g * 8;
    float4 a = *(const float4*)p;
    float4 b = *(const float4*)(p + 4);
    float xs[8] = {a.x, a.y, a.z, a.w, b.x, b.y, b.z, b.w};
    short8 v;
#pragma unroll
    for (int j = 0; j < 8; ++j) v[j] = f2bf(f(xs[j], row));
    *(short8*)(dst + row * 64 + (g ^ (row & 7)) * 8) = v;
  }
}

// A/B fragment from swizzled row-major bf16 tile.
__device__ __forceinline__ short8 frag_ld(const short* __restrict__ buf,
                                          int rowbase, int hf, int lane) {
  int r = rowbase + (lane & 15);
  int g = (hf * 4 + (lane >> 4)) ^ (r & 7);
  return *(const short8*)(buf + r * 64 + g * 8);
}
// fragment from transposed padded tile [64][TPAD].
__device__ __forceinline__ short8 frag_ldT(const short* __restrict__ buf,
                                           int nbase, int g, int lane) {
  int r = nbase + (lane & 15);
  return *(const short8*)(buf + r * TPAD + g * 8);
}
// A fragment from pbuf [64][PPAD].
__device__ __forceinline__ short8 frag_ldP(const short* __restrict__ buf,
                                           int rowbase, int ks, int lane) {
  int r = rowbase + (lane & 15);
  int g = ks * 4 + (lane >> 4);
  return *(const short8*)(buf + r * PPAD + g * 8);
}

// ---------------- Kernel 1: k_pre = denom partials + chunk sums ----------------------
// Band tiles (kb>=qb-1) additionally store their exp'd P tile (bf16, banded for prev)
// so k_fused never recomputes the band QK.
extern "C" __global__ void __launch_bounds__(256)
k_pre(const float* __restrict__ Q, const float* __restrict__ K,
      const float* __restrict__ V, const float* __restrict__ mask,
      float* __restrict__ ws, float* __restrict__ part,
      short* __restrict__ pd, short* __restrict__ pp) {
  __shared__ short ldsA[64 * TPAD];
  __shared__ short ldsB[64 * TPAD];
  __shared__ float fmsk[C_];
  const int orig = blockIdx.x;                       // 2432 = 8 * 304
  const int swz = (orig & 7) * 304 + (orig >> 3);
  const int t = threadIdx.x;
  const int w = t >> 6, lane = t & 63;
  const int col_lo = lane & 15;

  if (swz < 2176) {
    // ---------------- denom role ----------------
    const int nh = swz / 136;
    const int p = swz - nh * 136;
    int qb = (int)((sqrtf(8.f * p + 1.f) - 1.f) * 0.5f);
    while ((qb + 1) * (qb + 2) / 2 <= p) ++qb;
    while (qb * (qb + 1) / 2 > p) --qb;
    const int kb = p - qb * (qb + 1) / 2;
    const int h = nh & (H_ - 1), n = nh >> 3;

    stage_tile(ldsA, Q + ((n * L_ + qb * C_) * H_ + h) * E_,
               [](float x, int) { return x; });
    stage_tile(ldsB, K + ((n * L_ + kb * C_) * H_ + h) * E_,
               [](float x, int) { return x; });
    if (t < C_) fmsk[t] = mask[n * L_ + kb * C_ + t];
    __syncthreads();

    const int rowbase = w * 32;
    short8 afr[2][2];
#pragma unroll
    for (int m = 0; m < 2; ++m)
#pragma unroll
      for (int hh = 0; hh < 2; ++hh)
        afr[m][hh] = frag_ld(ldsA, rowbase + 16 * m, hh, lane);

    f32x4 acc[2][8];
#pragma unroll
    for (int m = 0; m < 2; ++m)
#pragma unroll
      for (int c = 0; c < 8; ++c) acc[m][c] = (f32x4){0.f, 0.f, 0.f, 0.f};

#pragma unroll
    for (int c = 0; c < 8; ++c) {
      short8 b0 = frag_ld(ldsB, 16 * c, 0, lane);
      short8 b1 = frag_ld(ldsB, 16 * c, 1, lane);
#pragma unroll
      for (int m = 0; m < 2; ++m) {
        acc[m][c] = __builtin_amdgcn_mfma_f32_16x16x32_bf16(afr[m][0], b0, acc[m][c], 0, 0, 0);
        acc[m][c] = __builtin_amdgcn_mfma_f32_16x16x32_bf16(afr[m][1], b1, acc[m][c], 0, 0, 0);
      }
    }

    const bool diag = (kb == qb);
    const bool prev = (kb == qb - 1);
    const bool band = diag || prev;
    short* pt = (diag ? pd : pp) + (size_t)(nh * NC + qb) * (C_ * C_);
    float* pout = part + (size_t)(nh * NC + qb) * C_ * 16;
#pragma unroll
    for (int m = 0; m < 2; ++m) {
      const int rbase = rowbase + 16 * m + ((lane >> 4) << 2);
      float rs[4] = {0.f, 0.f, 0.f, 0.f};
#pragma unroll
      for (int c = 0; c < 8; ++c) {
        const int col = 16 * c + col_lo;
        const float madd = (fmsk[col] > 0.f) ? 0.f : NEG_INF_F;
#pragma unroll
        for (int reg = 0; reg < 4; ++reg) {
          float x = acc[m][c][reg] + madd;
          if (diag && col > rbase + reg) x += NEG_INF_F;
          float e = __expf(x * TEMP);
          rs[reg] += e;                              // denominator: full causal range
          if (band) {
            if (prev && col < rbase + reg) e = 0.f;  // band: keep s >= l - 128
            pt[(rbase + reg) * C_ + col] = f2bf(e);
          }
        }
      }
#pragma unroll
      for (int off = 1; off < 16; off <<= 1) {
#pragma unroll
        for (int reg = 0; reg < 4; ++reg) rs[reg] += __shfl_xor(rs[reg], off);
      }
      if (col_lo == 0) {
#pragma unroll
        for (int reg = 0; reg < 4; ++reg) pout[(rbase + reg) * 16 + kb] = rs[reg];
      }
    }
  } else {
    // ---------------- chunk-sums role (bf16 MFMA) ----------------
    const int id = swz - 2176;               // 0..255
    const int nh = id >> 4, c = id & 15;
    const int h = nh & (H_ - 1), n = nh >> 3;
    const int gbase = ((n * L_ + c * C_) * H_ + h) * E_;
    const int e = t & 63, sb = t >> 6;
    const int mbase = n * L_ + c * C_;
#pragma unroll
    for (int q = 0; q < 4; ++q) {
      int s0 = sb * 32 + q * 8;
      short8 kk, vv;
#pragma unroll
      for (int j = 0; j < 8; ++j) {
        float kx = K[gbase + (s0 + j) * ROWSTRIDE + e];
        kk[j] = f2bf(tanh1f(kx) * mask[mbase + s0 + j]);
        vv[j] = f2bf(V[gbase + (s0 + j) * ROWSTRIDE + e]);
      }
      *(short8*)(ldsA + e * TPAD + (s0 >> 3) * 8) = kk;
      *(short8*)(ldsB + e * TPAD + (s0 >> 3) * 8) = vv;
    }
    __syncthreads();

    f32x4 acc[4];
#pragma unroll
    for (int nn = 0; nn < 4; ++nn) acc[nn] = (f32x4){0.f, 0.f, 0.f, 0.f};
#pragma unroll
    for (int ks = 0; ks < 4; ++ks) {
      short8 a = frag_ldT(ldsB, 16 * w, ks * 4 + (lane >> 4), lane);
#pragma unroll
      for (int nn = 0; nn < 4; ++nn) {
        short8 b = frag_ldT(ldsA, 16 * nn, ks * 4 + (lane >> 4), lane);
        acc[nn] = __builtin_amdgcn_mfma_f32_16x16x32_bf16(a, b, acc[nn], 0, 0, 0);
      }
    }
    float* wsc = ws + (size_t)(nh * NC + c) * CHUNK_WS;
    const int drow = 16 * w + ((lane >> 4) << 2);
#pragma unroll
    for (int nn = 0; nn < 4; ++nn)
#pragma unroll
      for (int reg = 0; reg < 4; ++reg)
        wsc[(16 * nn + col_lo) * D_ + drow + reg] = acc[nn][reg];
    if (t < 64) {
      float s = 0.f;
#pragma unroll
      for (int g = 0; g < 16; ++g) {
        short8 v = *(const short8*)(ldsA + t * TPAD + g * 8);
#pragma unroll
        for (int j = 0; j < 8; ++j) s += bf2f(v[j]);
      }
      wsc[E_ * D_ + t] = s;
    }
  }
}

// ---------------- Kernel 2: exclusive prefix scan, element-parallel ------------------
extern "C" __global__ void __launch_bounds__(256)
k_scan(float* __restrict__ ws) {
  const int bid = blockIdx.x;                        // 272 = 8 * 34
  const int swz = (bid & 7) * 34 + (bid >> 3);
  const int nh = swz / 17, seg = swz - nh * 17;
  const int idx = seg * 256 + threadIdx.x;
  if (idx >= CHUNK_WS) return;
  float* base = ws + (size_t)nh * NC * CHUNK_WS + idx;
  float v[NC];
#pragma unroll
  for (int c = 0; c < NC; ++c) v[c] = base[(size_t)c * CHUNK_WS];
  float acc = 0.f;
#pragma unroll
  for (int c = 0; c < NC; ++c) {
    base[(size_t)c * CHUNK_WS] = acc;
    acc += v[c];
  }
}

// ---------------- Kernel 3: fused — no band QK; consumes precomputed P tiles ---------
extern "C" __global__ void __launch_bounds__(256, 2)
k_fused(const float* __restrict__ Q, const float* __restrict__ K,
        const float* __restrict__ V, const float* __restrict__ mask,
        const float* __restrict__ blend, const float* __restrict__ ws,
        const float* __restrict__ part, const short* __restrict__ pd,
        const short* __restrict__ pp, float* __restrict__ out) {
  __shared__ short kbuf[C_ * 64];    // K1 (swizzled)
  __shared__ short kv[64 * TPAD];    // S^T -> V^T_cur -> V^T_prev
  __shared__ short pbuf[64 * PPAD];  // wave-private P half-tiles
  __shared__ float zlds[64];
  __shared__ float dinv[64];
  __shared__ float ksum[E_];

  const int orig = blockIdx.x;                      // 512 = 8 * 64
  const int swz = (orig & 7) * 64 + (orig >> 3);
  const int rh = swz & 1, qb = (swz >> 1) & (NC - 1), nh = swz >> 5;
  const int h = nh & (H_ - 1), n = nh >> 3;
  const int t = threadIdx.x;
  const int w = t >> 6, lane = t & 63;
  const int rowbase = w * 16;
  const int col_lo = lane & 15;
  const int rb = rowbase + ((lane >> 4) << 2);
  const int rtile0 = rh * 64 + rb;
  const int qgbase = ((n * L_ + qb * C_ + rh * 64) * H_ + h) * E_;
  const int kbase_chunk = ((n * L_ + qb * C_) * H_ + h) * E_;
  const float* wsc = ws + (size_t)(nh * NC + qb) * CHUNK_WS;
  const float bl = blend[0];
  const float ob = 1.f - bl;
  const int d = t & 63, sb = t >> 6;
  const bool haveprev = (qb > 0);
  const int kgp = ((n * L_ + (qb - 1) * C_) * H_ + h) * E_;

  // ===== seg0: stage K1 (LDS), S^T (LDS), dinv/ksum =====
  {
    const float* mrow = mask + n * L_ + qb * C_;
#pragma unroll
    for (int it = 0; it < 4; ++it) {
      int gi = it * 256 + t, row = gi >> 3, g = gi & 7;
      const float* p = K + kbase_chunk + row * ROWSTRIDE + g * 8;
      float4 a = *(const float4*)p, b = *(const float4*)(p + 4);
      float km = mrow[row];
      float xs[8] = {a.x, a.y, a.z, a.w, b.x, b.y, b.z, b.w};
      short8 v1;
#pragma unroll
      for (int j = 0; j < 8; ++j) v1[j] = f2bf(tanh1f(xs[j]) * km);
      *(short8*)(kbuf + row * 64 + (g ^ (row & 7)) * 8) = v1;
    }
  }
  {  // S^T into kv
    int eb = t >> 6;
#pragma unroll
    for (int q = 0; q < 2; ++q) {
      int e0 = eb * 16 + q * 8;
      short8 v;
#pragma unroll
      for (int j = 0; j < 8; ++j) v[j] = f2bf(wsc[(e0 + j) * D_ + d]);
      *(short8*)(kv + d * TPAD + (e0 >> 3) * 8) = v;
    }
  }
  if (t < 64) {
    ksum[t] = wsc[E_ * D_ + t];
    const float* pb = part + ((size_t)(nh * NC + qb) * C_ + rh * 64 + t) * 16;
    float4 a = *(const float4*)pb, b = *(const float4*)(pb + 4);
    float4 c = *(const float4*)(pb + 8), d4 = *(const float4*)(pb + 12);
    float vv[16] = {a.x, a.y, a.z, a.w, b.x, b.y, b.z, b.w,
                    c.x, c.y, c.z, c.w, d4.x, d4.y, d4.z, d4.w};
    float s = 0.f;
#pragma unroll
    for (int j = 0; j < 16; ++j) s += (j <= qb) ? vv[j] : 0.f;
    dinv[t] = 1.f / s;
  }
  __syncthreads();   // B1

  // ===== seg1: af1 (Q from global), c1 = Q1K1^T, rowsum, zpart, accO = Q1@S^T =====
  short8 af1[2];
  {
    const float* qp = Q + qgbase + (rowbase + (lane & 15)) * ROWSTRIDE;
#pragma unroll
    for (int kh = 0; kh < 2; ++kh) {
      int c0 = (kh * 4 + (lane >> 4)) * 8;
      float4 a = *(const float4*)(qp + c0);
      float4 b = *(const float4*)(qp + c0 + 4);
      float xs[8] = {a.x, a.y, a.z, a.w, b.x, b.y, b.z, b.w};
#pragma unroll
      for (int j = 0; j < 8; ++j) af1[kh][j] = f2bf(tanh1f(xs[j]));
    }
  }
  f32x4 c1[8];
#pragma unroll
  for (int ct = 0; ct < 8; ++ct) c1[ct] = (f32x4){0.f, 0.f, 0.f, 0.f};
#pragma unroll
  for (int ct = 0; ct < 8; ++ct) {
    short8 b0 = frag_ld(kbuf, 16 * ct, 0, lane);
    short8 b1 = frag_ld(kbuf, 16 * ct, 1, lane);
    c1[ct] = __builtin_amdgcn_mfma_f32_16x16x32_bf16(af1[0], b0, c1[ct], 0, 0, 0);
    c1[ct] = __builtin_amdgcn_mfma_f32_16x16x32_bf16(af1[1], b1, c1[ct], 0, 0, 0);
  }
  {  // zpart = Q1 . Ksum_start
    float zz = 0.f;
#pragma unroll
    for (int kh = 0; kh < 2; ++kh) {
      int cb = (kh * 4 + (lane >> 4)) * 8;
#pragma unroll
      for (int j = 0; j < 8; ++j) zz += bf2f(af1[kh][j]) * ksum[cb + j];
    }
    zz += __shfl_xor(zz, 16);
    zz += __shfl_xor(zz, 32);
    if (lane < 16) zlds[rowbase + lane] = zz;
  }
  float rs[4] = {0.f, 0.f, 0.f, 0.f};
#pragma unroll
  for (int ct = 0; ct < 8; ++ct) {
    int col = 16 * ct + col_lo;
#pragma unroll
    for (int reg = 0; reg < 4; ++reg) {
      if (col <= rtile0 + reg) rs[reg] += c1[ct][reg];
      else c1[ct][reg] = 0.f;
    }
  }
#pragma unroll
  for (int off = 1; off < 16; off <<= 1)
#pragma unroll
    for (int reg = 0; reg < 4; ++reg) rs[reg] += __shfl_xor(rs[reg], off);

  f32x4 accO[4];
#pragma unroll
  for (int nn = 0; nn < 4; ++nn) accO[nn] = (f32x4){0.f, 0.f, 0.f, 0.f};
#pragma unroll
  for (int ks = 0; ks < 2; ++ks) {
    short8 bf[4];
#pragma unroll
    for (int nn = 0; nn < 4; ++nn)
      bf[nn] = frag_ldT(kv, 16 * nn, ks * 4 + (lane >> 4), lane);
#pragma unroll
    for (int nn = 0; nn < 4; ++nn)
      accO[nn] = __builtin_amdgcn_mfma_f32_16x16x32_bf16(af1[ks], bf[nn], accO[nn], 0, 0, 0);
  }
  float zrf[4], sdv[4];
#pragma unroll
  for (int reg = 0; reg < 4; ++reg) {
    zrf[reg] = ob / (zlds[rb + reg] + rs[reg] + EPS_F);
    sdv[reg] = bl * dinv[rb + reg];
  }
#pragma unroll
  for (int nn = 0; nn < 4; ++nn)
#pragma unroll
    for (int reg = 0; reg < 4; ++reg) accO[nn][reg] *= zrf[reg];
#pragma unroll
  for (int ct = 0; ct < 8; ++ct)
#pragma unroll
    for (int reg = 0; reg < 4; ++reg) c1[ct][reg] *= zrf[reg];
  __syncthreads();   // B2: kbuf + kv(S^T) free

  // ===== seg2: stage V^T_cur into kv =====
#pragma unroll
  for (int q = 0; q < 4; ++q) {
    int s0 = sb * 32 + q * 8;
    short8 v;
#pragma unroll
    for (int j = 0; j < 8; ++j) v[j] = f2bf(V[kbase_chunk + (s0 + j) * ROWSTRIDE + d]);
    *(short8*)(kv + d * TPAD + (s0 >> 3) * 8) = v;
  }
  __syncthreads();   // B3

  // ===== seg3: accO += P1_hat @ V_cur (pbuf wave-local) =====
#pragma unroll
  for (int hh = 0; hh < 2; ++hh) {
#pragma unroll
    for (int cc = 0; cc < 4; ++cc) {
      int ct = 4 * hh + cc, colh = 16 * cc + col_lo;
#pragma unroll
      for (int reg = 0; reg < 4; ++reg)
        pbuf[(rb + reg) * PPAD + colh] = f2bf(c1[ct][reg]);
    }
#pragma unroll
    for (int ks = 0; ks < 2; ++ks) {
      short8 ap = frag_ldP(pbuf, rowbase, ks, lane);
      short8 bv[4];
#pragma unroll
      for (int nn = 0; nn < 4; ++nn)
        bv[nn] = frag_ldT(kv, 16 * nn, 8 * hh + ks * 4 + (lane >> 4), lane);
#pragma unroll
      for (int nn = 0; nn < 4; ++nn)
        accO[nn] = __builtin_amdgcn_mfma_f32_16x16x32_bf16(ap, bv[nn], accO[nn], 0, 0, 0);
    }
  }

  // ===== seg3b: diag P tile (precomputed) -> pbuf -> PV into accS =====
  f32x4 accS[4];
#pragma unroll
  for (int nn = 0; nn < 4; ++nn) accS[nn] = (f32x4){0.f, 0.f, 0.f, 0.f};
  {
    const short* ps = pd + (size_t)(nh * NC + qb) * (C_ * C_) + (size_t)(rh * 64) * C_;
#pragma unroll
    for (int hh = 0; hh < 2; ++hh) {
#pragma unroll
      for (int i = 0; i < 2; ++i) {   // wave-private copy of 16 rows x 64 cols half
        int idx = i * 64 + lane;
        int rl = rowbase + (idx >> 3), g = idx & 7;
        short8 v = *(const short8*)(ps + (size_t)rl * C_ + 64 * hh + g * 8);
        *(short8*)(pbuf + rl * PPAD + g * 8) = v;
      }
#pragma unroll
      for (int ks = 0; ks < 2; ++ks) {
        short8 ap = frag_ldP(pbuf, rowbase, ks, lane);
        short8 bv[4];
#pragma unroll
        for (int nn = 0; nn < 4; ++nn)
          bv[nn] = frag_ldT(kv, 16 * nn, 8 * hh + ks * 4 + (lane >> 4), lane);
#pragma unroll
        for (int nn = 0; nn < 4; ++nn)
          accS[nn] = __builtin_amdgcn_mfma_f32_16x16x32_bf16(ap, bv[nn], accS[nn], 0, 0, 0);
      }
    }
  }

  // ===== seg4/5: prev band tile =====
  if (haveprev) {
    __syncthreads();   // B4
#pragma unroll
    for (int q = 0; q < 4; ++q) {
      int s0 = sb * 32 + q * 8;
      short8 v;
#pragma unroll
      for (int j = 0; j < 8; ++j) v[j] = f2bf(V[kgp + (s0 + j) * ROWSTRIDE + d]);
      *(short8*)(kv + d * TPAD + (s0 >> 3) * 8) = v;
    }
    __syncthreads();   // B5

    const short* ps = pp + (size_t)(nh * NC + qb) * (C_ * C_) + (size_t)(rh * 64) * C_;
#pragma unroll
    for (int hh = 0; hh < 2; ++hh) {
#pragma unroll
      for (int i = 0; i < 2; ++i) {
        int idx = i * 64 + lane;
        int rl = rowbase + (idx >> 3), g = idx & 7;
        short8 v = *(const short8*)(ps + (size_t)rl * C_ + 64 * hh + g * 8);
        *(short8*)(pbuf + rl * PPAD + g * 8) = v;
      }
#pragma unroll
      for (int ks = 0; ks < 2; ++ks) {
        short8 ap = frag_ldP(pbuf, rowbase, ks, lane);
        short8 bv[4];
#pragma unroll
        for (int nn = 0; nn < 4; ++nn)
          bv[nn] = frag_ldT(kv, 16 * nn, 8 * hh + ks * 4 + (lane >> 4), lane);
#pragma unroll
        for (int nn = 0; nn < 4; ++nn)
          accS[nn] = __builtin_amdgcn_mfma_f32_16x16x32_bf16(ap, bv[nn], accS[nn], 0, 0, 0);
      }
    }
  }

  // ===== final store: out = (folded linear) + sdv * SV_raw =====
#pragma unroll
  for (int nn = 0; nn < 4; ++nn)
#pragma unroll
    for (int reg = 0; reg < 4; ++reg)
      out[qgbase + (rb + reg) * ROWSTRIDE + 16 * nn + col_lo] =
          accO[nn][reg] + sdv[reg] * accS[nn][reg];
}

extern "C" void kernel_launch(void* const* d_in, const int* in_sizes, int n_in,
                              void* d_out, int out_size, void* d_ws, size_t ws_size,
                              hipStream_t stream) {
  (void)in_sizes; (void)n_in; (void)out_size; (void)ws_size;
  const float* Q = (const float*)d_in[0];
  const float* K = (const float*)d_in[1];
  const float* V = (const float*)d_in[2];
  const float* mask = (const float*)d_in[3];
  const float* blend = (const float*)d_in[4];
  float* out = (float*)d_out;
  float* ws = (float*)d_ws;
  // layout (floats): chunk state | part | P_diag (bf16) | P_prev (bf16)  ~22.3 MB
  float* part = ws + (size_t)NCHUNKS * CHUNK_WS;
  short* pd = (short*)(part + (size_t)NCHUNKS * C_ * 16);
  short* pp = pd + (size_t)NCHUNKS * C_ * C_;

  k_pre<<<dim3(2432), dim3(256), 0, stream>>>(Q, K, V, mask, ws, part, pd, pp);
  k_scan<<<dim3(272), dim3(256), 0, stream>>>(ws);
  k_fused<<<dim3(N_ * H_ * NC * 2), dim3(256), 0, stream>>>(Q, K, V, mask, blend, ws, part, pd, pp, out);
}

// Round 16
// 45.426 us; speedup vs baseline: 1.1423x; 1.0115x over previous
//
#include <hip/hip_runtime.h>
#include <math.h>

#define N_ 2
#define L_ 2048
#define H_ 8
#define E_ 64
#define D_ 64
#define C_ 128                 // chunk size
#define NC (L_/C_)             // 16
#define ROWSTRIDE (H_*E_)      // 512 floats between consecutive l
#define TEMP 0.125f            // 1/sqrt(64)
#define EPS_F 1e-6f
#define NEG_INF_F (-1e9f)
#define CHUNK_WS (E_*D_ + E_)  // 4160 floats per (n,h,chunk) ws entry
#define NCHUNKS (N_*H_*NC)     // 256
#define TPAD 136               // transposed bf16 tile row stride (shorts)
#define PPAD 72                // pbuf row stride (shorts)
#define KV2 272                // wide kv row stride (shorts): S^T | V_cur^T coexist

typedef __attribute__((ext_vector_type(8))) short short8;   // 8 bf16 in 4 VGPRs
typedef __attribute__((ext_vector_type(4))) float f32x4;

__device__ __forceinline__ short f2bf(float x) {
  unsigned u = __float_as_uint(x);
  u += 0x7fffu + ((u >> 16) & 1u);   // round-to-nearest-even
  return (short)(u >> 16);
}
__device__ __forceinline__ float bf2f(short s) {
  return __uint_as_float(((unsigned)(unsigned short)s) << 16);
}
// tanh(x)+1 = 2/(1+exp(-2x))
__device__ __forceinline__ float tanh1f(float x) {
  float e = __expf(-2.f * x);
  return 2.f * __builtin_amdgcn_rcpf(1.f + e);
}

// Stage [128][64] f32 global tile -> swizzled bf16 LDS tile ([row][64]), f(x,row).
template <typename F>
__device__ __forceinline__ void stage_tile(short* __restrict__ dst,
                                           const float* __restrict__ src, F f) {
  const int t = threadIdx.x;
#pragma unroll
  for (int it = 0; it < 4; ++it) {
    int gi = it * 256 + t;
    int row = gi >> 3, g = gi & 7;
    const float* p = src + row * ROWSTRIDE + g * 8;
    float4 a = *(const float4*)p;
    float4 b = *(const float4*)(p + 4);
    float xs[8] = {a.x, a.y, a.z, a.w, b.x, b.y, b.z, b.w};
    short8 v;
#pragma unroll
    for (int j = 0; j < 8; ++j) v[j] = f2bf(f(xs[j], row));
    *(short8*)(dst + row * 64 + (g ^ (row & 7)) * 8) = v;
  }
}

// A/B fragment from swizzled row-major bf16 tile.
__device__ __forceinline__ short8 frag_ld(const short* __restrict__ buf,
                                          int rowbase, int hf, int lane) {
  int r = rowbase + (lane & 15);
  int g = (hf * 4 + (lane >> 4)) ^ (r & 7);
  return *(const short8*)(buf + r * 64 + g * 8);
}
// fragment from transposed padded tile [64][TPAD].
__device__ __forceinline__ short8 frag_ldT(const short* __restrict__ buf,
                                           int nbase, int g, int lane) {
  int r = nbase + (lane & 15);
  return *(const short8*)(buf + r * TPAD + g * 8);
}
// fragment from wide transposed tile [64][KV2]; g includes any column offset.
__device__ __forceinline__ short8 frag_ldT2(const short* __restrict__ buf,
                                            int nbase, int g, int lane) {
  int r = nbase + (lane & 15);
  return *(const short8*)(buf + r * KV2 + g * 8);
}
// A fragment from pbuf [64][PPAD].
__device__ __forceinline__ short8 frag_ldP(const short* __restrict__ buf,
                                           int rowbase, int ks, int lane) {
  int r = rowbase + (lane & 15);
  int g = ks * 4 + (lane >> 4);
  return *(const short8*)(buf + r * PPAD + g * 8);
}

// ---------------- Kernel 1: k_pre = denom partials + chunk sums (R15, unchanged) -----
extern "C" __global__ void __launch_bounds__(256)
k_pre(const float* __restrict__ Q, const float* __restrict__ K,
      const float* __restrict__ V, const float* __restrict__ mask,
      float* __restrict__ ws, float* __restrict__ part,
      short* __restrict__ pd, short* __restrict__ pp) {
  __shared__ short ldsA[64 * TPAD];
  __shared__ short ldsB[64 * TPAD];
  __shared__ float fmsk[C_];
  const int orig = blockIdx.x;                       // 2432 = 8 * 304
  const int swz = (orig & 7) * 304 + (orig >> 3);
  const int t = threadIdx.x;
  const int w = t >> 6, lane = t & 63;
  const int col_lo = lane & 15;

  if (swz < 2176) {
    // ---------------- denom role ----------------
    const int nh = swz / 136;
    const int p = swz - nh * 136;
    int qb = (int)((sqrtf(8.f * p + 1.f) - 1.f) * 0.5f);
    while ((qb + 1) * (qb + 2) / 2 <= p) ++qb;
    while (qb * (qb + 1) / 2 > p) --qb;
    const int kb = p - qb * (qb + 1) / 2;
    const int h = nh & (H_ - 1), n = nh >> 3;

    stage_tile(ldsA, Q + ((n * L_ + qb * C_) * H_ + h) * E_,
               [](float x, int) { return x; });
    stage_tile(ldsB, K + ((n * L_ + kb * C_) * H_ + h) * E_,
               [](float x, int) { return x; });
    if (t < C_) fmsk[t] = mask[n * L_ + kb * C_ + t];
    __syncthreads();

    const int rowbase = w * 32;
    short8 afr[2][2];
#pragma unroll
    for (int m = 0; m < 2; ++m)
#pragma unroll
      for (int hh = 0; hh < 2; ++hh)
        afr[m][hh] = frag_ld(ldsA, rowbase + 16 * m, hh, lane);

    f32x4 acc[2][8];
#pragma unroll
    for (int m = 0; m < 2; ++m)
#pragma unroll
      for (int c = 0; c < 8; ++c) acc[m][c] = (f32x4){0.f, 0.f, 0.f, 0.f};

#pragma unroll
    for (int c = 0; c < 8; ++c) {
      short8 b0 = frag_ld(ldsB, 16 * c, 0, lane);
      short8 b1 = frag_ld(ldsB, 16 * c, 1, lane);
#pragma unroll
      for (int m = 0; m < 2; ++m) {
        acc[m][c] = __builtin_amdgcn_mfma_f32_16x16x32_bf16(afr[m][0], b0, acc[m][c], 0, 0, 0);
        acc[m][c] = __builtin_amdgcn_mfma_f32_16x16x32_bf16(afr[m][1], b1, acc[m][c], 0, 0, 0);
      }
    }

    const bool diag = (kb == qb);
    const bool prev = (kb == qb - 1);
    const bool band = diag || prev;
    short* pt = (diag ? pd : pp) + (size_t)(nh * NC + qb) * (C_ * C_);
    float* pout = part + (size_t)(nh * NC + qb) * C_ * 16;
#pragma unroll
    for (int m = 0; m < 2; ++m) {
      const int rbase = rowbase + 16 * m + ((lane >> 4) << 2);
      float rs[4] = {0.f, 0.f, 0.f, 0.f};
#pragma unroll
      for (int c = 0; c < 8; ++c) {
        const int col = 16 * c + col_lo;
        const float madd = (fmsk[col] > 0.f) ? 0.f : NEG_INF_F;
#pragma unroll
        for (int reg = 0; reg < 4; ++reg) {
          float x = acc[m][c][reg] + madd;
          if (diag && col > rbase + reg) x += NEG_INF_F;
          float e = __expf(x * TEMP);
          rs[reg] += e;                              // denominator: full causal range
          if (band) {
            if (prev && col < rbase + reg) e = 0.f;  // band: keep s >= l - 128
            pt[(rbase + reg) * C_ + col] = f2bf(e);
          }
        }
      }
#pragma unroll
      for (int off = 1; off < 16; off <<= 1) {
#pragma unroll
        for (int reg = 0; reg < 4; ++reg) rs[reg] += __shfl_xor(rs[reg], off);
      }
      if (col_lo == 0) {
#pragma unroll
        for (int reg = 0; reg < 4; ++reg) pout[(rbase + reg) * 16 + kb] = rs[reg];
      }
    }
  } else {
    // ---------------- chunk-sums role (bf16 MFMA) ----------------
    const int id = swz - 2176;               // 0..255
    const int nh = id >> 4, c = id & 15;
    const int h = nh & (H_ - 1), n = nh >> 3;
    const int gbase = ((n * L_ + c * C_) * H_ + h) * E_;
    const int e = t & 63, sb = t >> 6;
    const int mbase = n * L_ + c * C_;
#pragma unroll
    for (int q = 0; q < 4; ++q) {
      int s0 = sb * 32 + q * 8;
      short8 kk, vv;
#pragma unroll
      for (int j = 0; j < 8; ++j) {
        float kx = K[gbase + (s0 + j) * ROWSTRIDE + e];
        kk[j] = f2bf(tanh1f(kx) * mask[mbase + s0 + j]);
        vv[j] = f2bf(V[gbase + (s0 + j) * ROWSTRIDE + e]);
      }
      *(short8*)(ldsA + e * TPAD + (s0 >> 3) * 8) = kk;
      *(short8*)(ldsB + e * TPAD + (s0 >> 3) * 8) = vv;
    }
    __syncthreads();

    f32x4 acc[4];
#pragma unroll
    for (int nn = 0; nn < 4; ++nn) acc[nn] = (f32x4){0.f, 0.f, 0.f, 0.f};
#pragma unroll
    for (int ks = 0; ks < 4; ++ks) {
      short8 a = frag_ldT(ldsB, 16 * w, ks * 4 + (lane >> 4), lane);
#pragma unroll
      for (int nn = 0; nn < 4; ++nn) {
        short8 b = frag_ldT(ldsA, 16 * nn, ks * 4 + (lane >> 4), lane);
        acc[nn] = __builtin_amdgcn_mfma_f32_16x16x32_bf16(a, b, acc[nn], 0, 0, 0);
      }
    }
    float* wsc = ws + (size_t)(nh * NC + c) * CHUNK_WS;
    const int drow = 16 * w + ((lane >> 4) << 2);
#pragma unroll
    for (int nn = 0; nn < 4; ++nn)
#pragma unroll
      for (int reg = 0; reg < 4; ++reg)
        wsc[(16 * nn + col_lo) * D_ + drow + reg] = acc[nn][reg];
    if (t < 64) {
      float s = 0.f;
#pragma unroll
      for (int g = 0; g < 16; ++g) {
        short8 v = *(const short8*)(ldsA + t * TPAD + g * 8);
#pragma unroll
        for (int j = 0; j < 8; ++j) s += bf2f(v[j]);
      }
      wsc[E_ * D_ + t] = s;
    }
  }
}

// ---------------- Kernel 2: exclusive prefix scan, element-parallel ------------------
extern "C" __global__ void __launch_bounds__(256)
k_scan(float* __restrict__ ws) {
  const int bid = blockIdx.x;                        // 272 = 8 * 34
  const int swz = (bid & 7) * 34 + (bid >> 3);
  const int nh = swz / 17, seg = swz - nh * 17;
  const int idx = seg * 256 + threadIdx.x;
  if (idx >= CHUNK_WS) return;
  float* base = ws + (size_t)nh * NC * CHUNK_WS + idx;
  float v[NC];
#pragma unroll
  for (int c = 0; c < NC; ++c) v[c] = base[(size_t)c * CHUNK_WS];
  float acc = 0.f;
#pragma unroll
  for (int c = 0; c < NC; ++c) {
    base[(size_t)c * CHUNK_WS] = acc;
    acc += v[c];
  }
}

// ---------------- Kernel 3: fused — wide kv (S^T | V_cur^T coexist), 3 barriers ------
extern "C" __global__ void __launch_bounds__(256, 2)
k_fused(const float* __restrict__ Q, const float* __restrict__ K,
        const float* __restrict__ V, const float* __restrict__ mask,
        const float* __restrict__ blend, const float* __restrict__ ws,
        const float* __restrict__ part, const short* __restrict__ pd,
        const short* __restrict__ pp, float* __restrict__ out) {
  __shared__ short kbuf[C_ * 64];    // K1 (swizzled)                       16 KB
  __shared__ short kv2[64 * KV2];    // cols 0:64 S^T -> V_prev^T(0:128); cols 136:264 V_cur^T  34 KB
  __shared__ short pbuf[64 * PPAD];  // wave-private P half-tiles            9 KB
  __shared__ float zlds[64];
  __shared__ float dinv[64];
  __shared__ float ksum[E_];

  const int orig = blockIdx.x;                      // 512 = 8 * 64
  const int swz = (orig & 7) * 64 + (orig >> 3);
  const int rh = swz & 1, qb = (swz >> 1) & (NC - 1), nh = swz >> 5;
  const int h = nh & (H_ - 1), n = nh >> 3;
  const int t = threadIdx.x;
  const int w = t >> 6, lane = t & 63;
  const int rowbase = w * 16;
  const int col_lo = lane & 15;
  const int rb = rowbase + ((lane >> 4) << 2);
  const int rtile0 = rh * 64 + rb;
  const int qgbase = ((n * L_ + qb * C_ + rh * 64) * H_ + h) * E_;
  const int kbase_chunk = ((n * L_ + qb * C_) * H_ + h) * E_;
  const float* wsc = ws + (size_t)(nh * NC + qb) * CHUNK_WS;
  const float bl = blend[0];
  const float ob = 1.f - bl;
  const int d = t & 63, sb = t >> 6;
  const bool haveprev = (qb > 0);
  const int kgp = ((n * L_ + (qb - 1) * C_) * H_ + h) * E_;

  // ===== seg0: stage K1, S^T (kv2 cols 0:64), V_cur^T (kv2 cols 136:264), dinv/ksum =====
  {
    const float* mrow = mask + n * L_ + qb * C_;
#pragma unroll
    for (int it = 0; it < 4; ++it) {
      int gi = it * 256 + t, row = gi >> 3, g = gi & 7;
      const float* p = K + kbase_chunk + row * ROWSTRIDE + g * 8;
      float4 a = *(const float4*)p, b = *(const float4*)(p + 4);
      float km = mrow[row];
      float xs[8] = {a.x, a.y, a.z, a.w, b.x, b.y, b.z, b.w};
      short8 v1;
#pragma unroll
      for (int j = 0; j < 8; ++j) v1[j] = f2bf(tanh1f(xs[j]) * km);
      *(short8*)(kbuf + row * 64 + (g ^ (row & 7)) * 8) = v1;
    }
  }
  {  // S^T into kv2 cols 0:64
    int eb = t >> 6;
#pragma unroll
    for (int q = 0; q < 2; ++q) {
      int e0 = eb * 16 + q * 8;
      short8 v;
#pragma unroll
      for (int j = 0; j < 8; ++j) v[j] = f2bf(wsc[(e0 + j) * D_ + d]);
      *(short8*)(kv2 + d * KV2 + (eb * 2 + q) * 8) = v;
    }
  }
  {  // V_cur^T into kv2 cols 136:264 (granules 17..32)
#pragma unroll
    for (int q = 0; q < 4; ++q) {
      int s0 = sb * 32 + q * 8;
      short8 v;
#pragma unroll
      for (int j = 0; j < 8; ++j) v[j] = f2bf(V[kbase_chunk + (s0 + j) * ROWSTRIDE + d]);
      *(short8*)(kv2 + d * KV2 + (17 + sb * 4 + q) * 8) = v;
    }
  }
  if (t < 64) {
    ksum[t] = wsc[E_ * D_ + t];
    const float* pb = part + ((size_t)(nh * NC + qb) * C_ + rh * 64 + t) * 16;
    float4 a = *(const float4*)pb, b = *(const float4*)(pb + 4);
    float4 c = *(const float4*)(pb + 8), d4 = *(const float4*)(pb + 12);
    float vv[16] = {a.x, a.y, a.z, a.w, b.x, b.y, b.z, b.w,
                    c.x, c.y, c.z, c.w, d4.x, d4.y, d4.z, d4.w};
    float s = 0.f;
#pragma unroll
    for (int j = 0; j < 16; ++j) s += (j <= qb) ? vv[j] : 0.f;
    dinv[t] = 1.f / s;
  }
  __syncthreads();   // B1 (only barrier until prev tile)

  // ===== seg1: Q frags, V_prev reg prefetch, c1 = Q1K1^T, rowsum, zpart, accO =====
  short8 af1[2];
  {
    const float* qp = Q + qgbase + (rowbase + (lane & 15)) * ROWSTRIDE;
#pragma unroll
    for (int kh = 0; kh < 2; ++kh) {
      int c0 = (kh * 4 + (lane >> 4)) * 8;
      float4 a = *(const float4*)(qp + c0);
      float4 b = *(const float4*)(qp + c0 + 4);
      float xs[8] = {a.x, a.y, a.z, a.w, b.x, b.y, b.z, b.w};
#pragma unroll
      for (int j = 0; j < 8; ++j) af1[kh][j] = f2bf(tanh1f(xs[j]));
    }
  }
  short8 vpre[4];   // V_prev^T prefetch (latency hidden under seg1-3)
  if (haveprev) {
#pragma unroll
    for (int q = 0; q < 4; ++q) {
      int s0 = sb * 32 + q * 8;
#pragma unroll
      for (int j = 0; j < 8; ++j)
        vpre[q][j] = f2bf(V[kgp + (s0 + j) * ROWSTRIDE + d]);
    }
  }
  f32x4 c1[8];
#pragma unroll
  for (int ct = 0; ct < 8; ++ct) c1[ct] = (f32x4){0.f, 0.f, 0.f, 0.f};
#pragma unroll
  for (int ct = 0; ct < 8; ++ct) {
    short8 b0 = frag_ld(kbuf, 16 * ct, 0, lane);
    short8 b1 = frag_ld(kbuf, 16 * ct, 1, lane);
    c1[ct] = __builtin_amdgcn_mfma_f32_16x16x32_bf16(af1[0], b0, c1[ct], 0, 0, 0);
    c1[ct] = __builtin_amdgcn_mfma_f32_16x16x32_bf16(af1[1], b1, c1[ct], 0, 0, 0);
  }
  {  // zpart = Q1 . Ksum_start
    float zz = 0.f;
#pragma unroll
    for (int kh = 0; kh < 2; ++kh) {
      int cb = (kh * 4 + (lane >> 4)) * 8;
#pragma unroll
      for (int j = 0; j < 8; ++j) zz += bf2f(af1[kh][j]) * ksum[cb + j];
    }
    zz += __shfl_xor(zz, 16);
    zz += __shfl_xor(zz, 32);
    if (lane < 16) zlds[rowbase + lane] = zz;
  }
  float rs[4] = {0.f, 0.f, 0.f, 0.f};
#pragma unroll
  for (int ct = 0; ct < 8; ++ct) {
    int col = 16 * ct + col_lo;
#pragma unroll
    for (int reg = 0; reg < 4; ++reg) {
      if (col <= rtile0 + reg) rs[reg] += c1[ct][reg];
      else c1[ct][reg] = 0.f;
    }
  }
#pragma unroll
  for (int off = 1; off < 16; off <<= 1)
#pragma unroll
    for (int reg = 0; reg < 4; ++reg) rs[reg] += __shfl_xor(rs[reg], off);

  f32x4 accO[4];
#pragma unroll
  for (int nn = 0; nn < 4; ++nn) accO[nn] = (f32x4){0.f, 0.f, 0.f, 0.f};
#pragma unroll
  for (int ks = 0; ks < 2; ++ks) {
    short8 bf[4];
#pragma unroll
    for (int nn = 0; nn < 4; ++nn)
      bf[nn] = frag_ldT2(kv2, 16 * nn, ks * 4 + (lane >> 4), lane);
#pragma unroll
    for (int nn = 0; nn < 4; ++nn)
      accO[nn] = __builtin_amdgcn_mfma_f32_16x16x32_bf16(af1[ks], bf[nn], accO[nn], 0, 0, 0);
  }
  float zrf[4], sdv[4];
#pragma unroll
  for (int reg = 0; reg < 4; ++reg) {
    zrf[reg] = ob / (zlds[rb + reg] + rs[reg] + EPS_F);
    sdv[reg] = bl * dinv[rb + reg];
  }
#pragma unroll
  for (int nn = 0; nn < 4; ++nn)
#pragma unroll
    for (int reg = 0; reg < 4; ++reg) accO[nn][reg] *= zrf[reg];
#pragma unroll
  for (int ct = 0; ct < 8; ++ct)
#pragma unroll
    for (int reg = 0; reg < 4; ++reg) c1[ct][reg] *= zrf[reg];

  // ===== seg2: accO += P1_hat @ V_cur (pbuf wave-local; V_cur already staged) =====
#pragma unroll
  for (int hh = 0; hh < 2; ++hh) {
#pragma unroll
    for (int cc = 0; cc < 4; ++cc) {
      int ct = 4 * hh + cc, colh = 16 * cc + col_lo;
#pragma unroll
      for (int reg = 0; reg < 4; ++reg)
        pbuf[(rb + reg) * PPAD + colh] = f2bf(c1[ct][reg]);
    }
#pragma unroll
    for (int ks = 0; ks < 2; ++ks) {
      short8 ap = frag_ldP(pbuf, rowbase, ks, lane);
      short8 bv[4];
#pragma unroll
      for (int nn = 0; nn < 4; ++nn)
        bv[nn] = frag_ldT2(kv2, 16 * nn, 17 + 8 * hh + ks * 4 + (lane >> 4), lane);
#pragma unroll
      for (int nn = 0; nn < 4; ++nn)
        accO[nn] = __builtin_amdgcn_mfma_f32_16x16x32_bf16(ap, bv[nn], accO[nn], 0, 0, 0);
    }
  }

  // ===== seg3: diag P tile (precomputed) -> pbuf -> PV into accS =====
  f32x4 accS[4];
#pragma unroll
  for (int nn = 0; nn < 4; ++nn) accS[nn] = (f32x4){0.f, 0.f, 0.f, 0.f};
  {
    const short* ps = pd + (size_t)(nh * NC + qb) * (C_ * C_) + (size_t)(rh * 64) * C_;
#pragma unroll
    for (int hh = 0; hh < 2; ++hh) {
#pragma unroll
      for (int i = 0; i < 2; ++i) {   // wave-private copy of 16 rows x 64-col half
        int idx = i * 64 + lane;
        int rl = rowbase + (idx >> 3), g = idx & 7;
        short8 v = *(const short8*)(ps + (size_t)rl * C_ + 64 * hh + g * 8);
        *(short8*)(pbuf + rl * PPAD + g * 8) = v;
      }
#pragma unroll
      for (int ks = 0; ks < 2; ++ks) {
        short8 ap = frag_ldP(pbuf, rowbase, ks, lane);
        short8 bv[4];
#pragma unroll
        for (int nn = 0; nn < 4; ++nn)
          bv[nn] = frag_ldT2(kv2, 16 * nn, 17 + 8 * hh + ks * 4 + (lane >> 4), lane);
#pragma unroll
        for (int nn = 0; nn < 4; ++nn)
          accS[nn] = __builtin_amdgcn_mfma_f32_16x16x32_bf16(ap, bv[nn], accS[nn], 0, 0, 0);
      }
    }
  }

  // ===== seg4: prev band tile (V_prev from regs over dead S^T region) =====
  if (haveprev) {
    __syncthreads();   // B2: all waves done reading S^T cols (accL)
#pragma unroll
    for (int q = 0; q < 4; ++q)
      *(short8*)(kv2 + d * KV2 + (sb * 4 + q) * 8) = vpre[q];
    __syncthreads();   // B3

    const short* ps = pp + (size_t)(nh * NC + qb) * (C_ * C_) + (size_t)(rh * 64) * C_;
#pragma unroll
    for (int hh = 0; hh < 2; ++hh) {
#pragma unroll
      for (int i = 0; i < 2; ++i) {
        int idx = i * 64 + lane;
        int rl = rowbase + (idx >> 3), g = idx & 7;
        short8 v = *(const short8*)(ps + (size_t)rl * C_ + 64 * hh + g * 8);
        *(short8*)(pbuf + rl * PPAD + g * 8) = v;
      }
#pragma unroll
      for (int ks = 0; ks < 2; ++ks) {
        short8 ap = frag_ldP(pbuf, rowbase, ks, lane);
        short8 bv[4];
#pragma unroll
        for (int nn = 0; nn < 4; ++nn)
          bv[nn] = frag_ldT2(kv2, 16 * nn, 8 * hh + ks * 4 + (lane >> 4), lane);
#pragma unroll
        for (int nn = 0; nn < 4; ++nn)
          accS[nn] = __builtin_amdgcn_mfma_f32_16x16x32_bf16(ap, bv[nn], accS[nn], 0, 0, 0);
      }
    }
  }

  // ===== final store: out = (folded linear) + sdv * SV_raw =====
#pragma unroll
  for (int nn = 0; nn < 4; ++nn)
#pragma unroll
    for (int reg = 0; reg < 4; ++reg)
      out[qgbase + (rb + reg) * ROWSTRIDE + 16 * nn + col_lo] =
          accO[nn][reg] + sdv[reg] * accS[nn][reg];
}

extern "C" void kernel_launch(void* const* d_in, const int* in_sizes, int n_in,
                              void* d_out, int out_size, void* d_ws, size_t ws_size,
                              hipStream_t stream) {
  (void)in_sizes; (void)n_in; (void)out_size; (void)ws_size;
  const float* Q = (const float*)d_in[0];
  const float* K = (const float*)d_in[1];
  const float* V = (const float*)d_in[2];
  const float* mask = (const float*)d_in[3];
  const float* blend = (const float*)d_in[4];
  float* out = (float*)d_out;
  float* ws = (float*)d_ws;
  // layout (floats): chunk state | part | P_diag (bf16) | P_prev (bf16)  ~22.3 MB
  float* part = ws + (size_t)NCHUNKS * CHUNK_WS;
  short* pd = (short*)(part + (size_t)NCHUNKS * C_ * 16);
  short* pp = pd + (size_t)NCHUNKS * C_ * C_;

  k_pre<<<dim3(2432), dim3(256), 0, stream>>>(Q, K, V, mask, ws, part, pd, pp);
  k_scan<<<dim3(272), dim3(256), 0, stream>>>(ws);
  k_fused<<<dim3(N_ * H_ * NC * 2), dim3(256), 0, stream>>>(Q, K, V, mask, blend, ws, part, pd, pp, out);
}